// Round 13
// baseline (2015.831 us; speedup 1.0000x reference)
//
#include <hip/hip_runtime.h>
#include <hip/hip_bf16.h>

#define NN 100000
#define EE 1600000
#define HH 128
#define NDIM 91
#define EDIM 20
#define BB 128
#define EPSF 1e-5f
#define NBLK 4096
#define PER 400                 // edges per block (4 kg-subranges of 100)
#define ECAP (NBLK * PER)       // 1,638,400 (padded)
#define LN2I 1.44269504f
#define NPART 512               // bn_stats partial blocks

typedef __attribute__((ext_vector_type(8))) short short8v;
typedef __attribute__((ext_vector_type(4))) float f32x4;

__device__ __forceinline__ short f2bs(float x) {
  __hip_bfloat16 b = __float2bfloat16(x);
  return *reinterpret_cast<short*>(&b);
}
__device__ __forceinline__ float bl(unsigned int u) {  // lo bf16 -> f32
  union { unsigned int i; float f; } x; x.i = u << 16; return x.f;
}
__device__ __forceinline__ float bh(unsigned int u) {  // hi bf16 -> f32
  union { unsigned int i; float f; } x; x.i = u & 0xffff0000u; return x.f;
}

// ---------------- embed: h = nf @ W + b  (N x 91 @ 91 x 128) ----------------
__global__ __launch_bounds__(256) void k_embed(const float* __restrict__ nf,
                                               const float* __restrict__ W,
                                               const float* __restrict__ b,
                                               float* __restrict__ h) {
  __shared__ float w_s[NDIM * HH];
  __shared__ float b_s[HH];
  __shared__ float a_s[16 * 92];
  for (int i = threadIdx.x; i < NDIM * HH; i += 256) w_s[i] = W[i];
  if (threadIdx.x < HH) b_s[threadIdx.x] = b[threadIdx.x];
  __syncthreads();
  int col = threadIdx.x & 127, rs = threadIdx.x >> 7;
  for (int base = blockIdx.x * 16; base < NN; base += gridDim.x * 16) {
    int nrows = min(16, NN - base);
    int tot = nrows * NDIM;
    for (int i = threadIdx.x; i < tot; i += 256) {
      int r = i / NDIM;
      a_s[r * 92 + (i - r * NDIM)] = nf[(size_t)base * NDIM + i];
    }
    __syncthreads();
    float acc[8];
#pragma unroll
    for (int r = 0; r < 8; r++) acc[r] = 0.f;
    for (int k = 0; k < NDIM; k++) {
      float w = w_s[k * HH + col];
#pragma unroll
      for (int r = 0; r < 8; r++) acc[r] += a_s[(rs * 8 + r) * 92 + k] * w;
    }
#pragma unroll
    for (int r = 0; r < 8; r++) {
      int row = base + rs * 8 + r;
      if (row < NN) h[(size_t)row * HH + col] = acc[r] + b_s[col];
    }
    __syncthreads();
  }
}

// --- one-shot weight prep for ALL 3 layers + cnt zeroing --------------------
__global__ __launch_bounds__(256) void k_wprep3(const float* __restrict__ conv_wsrc,
                                                const float* __restrict__ conv_wdst,
                                                const float* __restrict__ conv_we,
                                                const float* __restrict__ conv_b,
                                                short* __restrict__ wt3,
                                                short* __restrict__ Web3,
                                                int* __restrict__ cnt) {
  int i = blockIdx.x * 256 + threadIdx.x;
  if (i < NN) cnt[i] = 0;
  if (i >= 3 * 73728) return;
  int layer = i / 73728;
  int j = i - layer * 73728;
  if (j < 65536) {
    int mat = j >> 15;
    int r = (j >> 7) & 255;
    int k = j & 127;
    const float* W = (mat ? conv_wdst : conv_wsrc) + (size_t)layer * HH * 256;
    wt3[(size_t)layer * 65536 + j] = f2bs(W[k * 256 + r]);
  } else {
    int jj = j - 65536;
    int c = jj >> 5, k = jj & 31;
    const float* We = conv_we + (size_t)layer * EDIM * 256;
    const float* bias = conv_b + (size_t)layer * 256;
    float v = (k < EDIM) ? We[k * 256 + c] : (k == EDIM ? bias[c] : 0.f);
    float sc = (c < 128) ? -LN2I : LN2I;
    Web3[(size_t)layer * 8192 + jj] = f2bs(v * sc);
  }
}

// ------------- node_mm (merged mats + fused BN-update + agg zeroing) -------
__global__ __launch_bounds__(256) void k_node_mm(float* __restrict__ h,
                                                 float* __restrict__ agg,
                                                 const float* __restrict__ stats,
                                                 const short* __restrict__ wt,
                                                 unsigned int* __restrict__ hs2,
                                                 unsigned int* __restrict__ hd2,
                                                 int apply) {
  __shared__ short hlds[64 * 128];  // 16 KB bf16 A-tile
  __shared__ float st_s[256];
  int base = blockIdx.x * 64;
  int t = threadIdx.x;
  if (apply) {
    if (t < 256) st_s[t] = stats[t];
    __syncthreads();
  }
  const float4 z4 = make_float4(0.f, 0.f, 0.f, 0.f);
#pragma unroll
  for (int p = 0; p < 4; p++) {
    int e0 = (p * 256 + t) * 8;
    int row = e0 >> 7, col = e0 & 127;
    int gr = base + row;
    float4 f0 = z4, f1 = z4;
    if (gr < NN) {
      f0 = *(const float4*)&h[(size_t)gr * 128 + col];
      f1 = *(const float4*)&h[(size_t)gr * 128 + col + 4];
      if (apply) {
        float4 a0 = *(const float4*)&agg[(size_t)gr * 128 + col];
        float4 a1 = *(const float4*)&agg[(size_t)gr * 128 + col + 4];
        f0.x = fmaxf(f0.x + a0.x * st_s[col] + st_s[128 + col], 0.f);
        f0.y = fmaxf(f0.y + a0.y * st_s[col + 1] + st_s[129 + col], 0.f);
        f0.z = fmaxf(f0.z + a0.z * st_s[col + 2] + st_s[130 + col], 0.f);
        f0.w = fmaxf(f0.w + a0.w * st_s[col + 3] + st_s[131 + col], 0.f);
        f1.x = fmaxf(f1.x + a1.x * st_s[col + 4] + st_s[132 + col], 0.f);
        f1.y = fmaxf(f1.y + a1.y * st_s[col + 5] + st_s[133 + col], 0.f);
        f1.z = fmaxf(f1.z + a1.z * st_s[col + 6] + st_s[134 + col], 0.f);
        f1.w = fmaxf(f1.w + a1.w * st_s[col + 7] + st_s[135 + col], 0.f);
        *(float4*)&h[(size_t)gr * 128 + col] = f0;
        *(float4*)&h[(size_t)gr * 128 + col + 4] = f1;
      }
      // zero agg for the next layer's edge accumulation (replaces memset)
      *(float4*)&agg[(size_t)gr * 128 + col] = z4;
      *(float4*)&agg[(size_t)gr * 128 + col + 4] = z4;
    }
    short8v u;
    u[0] = f2bs(f0.x); u[1] = f2bs(f0.y); u[2] = f2bs(f0.z); u[3] = f2bs(f0.w);
    u[4] = f2bs(f1.x); u[5] = f2bs(f1.y); u[6] = f2bs(f1.z); u[7] = f2bs(f1.w);
    *(short8v*)&hlds[e0] = u;
  }
  __syncthreads();
  int w = t >> 6, l = t & 63;
  int cl = l & 15, kg = l >> 4;
  bool full = (base + 64 <= NN);
  short8v a[4];
#pragma unroll
  for (int kk = 0; kk < 4; kk++)
    a[kk] = *(const short8v*)&hlds[(w * 16 + cl) * 128 + kk * 32 + kg * 8];
#pragma unroll
  for (int mat = 0; mat < 2; mat++) {
    const short* wtm = wt + mat * 256 * 128;
    unsigned int* out = mat ? hd2 : hs2;
    f32x4 acc[16];
#pragma unroll
    for (int ct = 0; ct < 16; ct++) acc[ct] = (f32x4)(0.f);
#pragma unroll
    for (int ct = 0; ct < 16; ct++) {
#pragma unroll
      for (int kk = 0; kk < 4; kk++) {
        short8v b = *(const short8v*)&wtm[(ct * 16 + cl) * 128 + kk * 32 + kg * 8];
        acc[ct] = __builtin_amdgcn_mfma_f32_16x16x32_bf16(a[kk], b, acc[ct], 0, 0, 0);
      }
    }
    // paired-column epilogue: ct=2j,2j+1 -> adjacent slots -> uint2 store
#pragma unroll
    for (int j = 0; j < 4; j++) {
#pragma unroll
      for (int r = 0; r < 4; r++) {
        int gr = base + w * 16 + kg * 4 + r;
        if (full || gr < NN) {
          unsigned short g0 = (unsigned short)f2bs(-LN2I * acc[2 * j][r]);
          unsigned short s0 = (unsigned short)f2bs(LN2I * acc[2 * j + 8][r]);
          unsigned short g1 = (unsigned short)f2bs(-LN2I * acc[2 * j + 1][r]);
          unsigned short s1 = (unsigned short)f2bs(LN2I * acc[2 * j + 9][r]);
          uint2 val;
          val.x = (unsigned int)g0 | ((unsigned int)s0 << 16);
          val.y = (unsigned int)g1 | ((unsigned int)s1 << 16);
          *(uint2*)&out[(size_t)gr * 128 + j * 32 + (cl << 1)] = val;
        }
      }
    }
  }
}

// ---------------- counting sort by dst: hist, scan, scatter -----------------
__global__ __launch_bounds__(256) void k_hist(const int* __restrict__ dst,
                                              int* __restrict__ cnt) {
  for (int e = blockIdx.x * 256 + threadIdx.x; e < EE; e += gridDim.x * 256)
    atomicAdd(&cnt[dst[e]], 1);
}

__global__ __launch_bounds__(1024) void k_scan(const int* __restrict__ cnt,
                                               int* __restrict__ off) {
  __shared__ int ps[1024];
  int t = threadIdx.x;
  const int R = (NN + 1023) / 1024;
  int b0 = t * R, b1 = min(NN, b0 + R);
  int s = 0;
  for (int i = b0; i < b1; i++) s += cnt[i];
  ps[t] = s;
  __syncthreads();
  for (int d = 1; d < 1024; d <<= 1) {
    int v = (t >= d) ? ps[t - d] : 0;
    __syncthreads();
    ps[t] += v;
    __syncthreads();
  }
  int run = (t == 0) ? 0 : ps[t - 1];
  for (int i = b0; i < b1; i++) {
    off[i] = run;
    run += cnt[i];
  }
}

// scatter (+tail pad): sorted idx + ef rows bf16 [32] (k20=1.0 bias hook)
__global__ __launch_bounds__(256) void k_scatter(const int* __restrict__ src,
                                                 const int* __restrict__ dst,
                                                 const float* __restrict__ ef,
                                                 int* __restrict__ off,
                                                 int* __restrict__ src_s,
                                                 int* __restrict__ dst_s,
                                                 short* __restrict__ efp) {
  for (int e = blockIdx.x * 256 + threadIdx.x; e < ECAP; e += gridDim.x * 256) {
    if (e < EE) {
      int d = dst[e];
      int pos = atomicAdd(&off[d], 1);
      src_s[pos] = src[e];
      dst_s[pos] = d;
      const float4* in = (const float4*)&ef[(size_t)e * EDIM];
      float4 q0 = in[0], q1 = in[1], q2 = in[2], q3 = in[3], q4 = in[4];
      short8v u0, u1, u2, u3;
      u0[0] = f2bs(q0.x); u0[1] = f2bs(q0.y); u0[2] = f2bs(q0.z); u0[3] = f2bs(q0.w);
      u0[4] = f2bs(q1.x); u0[5] = f2bs(q1.y); u0[6] = f2bs(q1.z); u0[7] = f2bs(q1.w);
      u1[0] = f2bs(q2.x); u1[1] = f2bs(q2.y); u1[2] = f2bs(q2.z); u1[3] = f2bs(q2.w);
      u1[4] = f2bs(q3.x); u1[5] = f2bs(q3.y); u1[6] = f2bs(q3.z); u1[7] = f2bs(q3.w);
      u2[0] = f2bs(q4.x); u2[1] = f2bs(q4.y); u2[2] = f2bs(q4.z); u2[3] = f2bs(q4.w);
      u2[4] = f2bs(1.0f); u2[5] = 0; u2[6] = 0; u2[7] = 0;
      u3 = (short8v)(short)0;
      short8v* op = (short8v*)&efp[(size_t)pos * 32];
      op[0] = u0; op[1] = u1; op[2] = u2; op[3] = u3;
    } else {
      src_s[e] = 0;
      dst_s[e] = -2;
      short8v z = (short8v)(short)0;
      short8v* op = (short8v*)&efp[(size_t)e * 32];
      op[0] = z; op[1] = z; op[2] = z; op[3] = z;
    }
  }
}

// ---- edge kernel v8 + occupancy hint (ONLY change vs round 12's edge):
// ---- barrier-free, zero LDS, run-cached hd, all loads hoisted out of the
// ---- divergent region. (256,8): 8 waves/EU allowed (VGPR 44 <= 64).
__global__ __launch_bounds__(256, 8) void k_edge_v8(
    const unsigned int* __restrict__ hs2, const unsigned int* __restrict__ hd2,
    const short* __restrict__ efp, const int* __restrict__ srcp,
    const int* __restrict__ dstp, const short* __restrict__ Web,
    float* __restrict__ agg) {
  const int i0 = blockIdx.x * PER;
  int t = threadIdx.x;
  int w = t >> 6, l = t & 63, cl = l & 15, kg = l >> 4;
  int c0 = w * 32 + cl, c1 = c0 + 16;
  int pairoff = w * 32 + (cl << 1);
  short8v bg0 = *(const short8v*)&Web[c0 * 32 + kg * 8];
  short8v bg1 = *(const short8v*)&Web[c1 * 32 + kg * 8];
  short8v bs0 = *(const short8v*)&Web[(128 + c0) * 32 + kg * 8];
  short8v bs1 = *(const short8v*)&Web[(128 + c1) * 32 + kg * 8];
  int cur = -1;
  float acc0 = 0.f, acc1 = 0.f;
  float hg0 = 0.f, hp0 = 0.f, hg1 = 0.f, hp1 = 0.f;
  const int o_a_base = i0 + (cl >> 2) * 100 + (cl & 3);
  const int o_e_base = i0 + kg * 100;
  for (int it = 0; it < 25; ++it) {
    int off4 = it * 4;
    short8v a = *(const short8v*)&efp[(size_t)(o_a_base + off4) * 32 + kg * 8];
    f32x4 zgv0 = __builtin_amdgcn_mfma_f32_16x16x32_bf16(a, bg0, (f32x4)(0.f), 0, 0, 0);
    f32x4 zgv1 = __builtin_amdgcn_mfma_f32_16x16x32_bf16(a, bg1, (f32x4)(0.f), 0, 0, 0);
    f32x4 zsv0 = __builtin_amdgcn_mfma_f32_16x16x32_bf16(a, bs0, (f32x4)(0.f), 0, 0, 0);
    f32x4 zsv1 = __builtin_amdgcn_mfma_f32_16x16x32_bf16(a, bs1, (f32x4)(0.f), 0, 0, 0);
    int o_e = o_e_base + off4;
    int4 s4 = *(const int4*)&srcp[o_e];
    int4 d4 = *(const int4*)&dstp[o_e];
    int ss[4] = {s4.x, s4.y, s4.z, s4.w};
    int dd[4] = {d4.x, d4.y, d4.z, d4.w};
    // hoisted gathers: hs2 per edge + unconditional hd2 (clamped, L1-repeated)
    uint2 us[4], xs[4];
#pragma unroll
    for (int r = 0; r < 4; ++r) {
      us[r] = *(const uint2*)&hs2[((size_t)ss[r] << 7) + pairoff];
      int dc = dd[r] < 0 ? 0 : dd[r];
      xs[r] = *(const uint2*)&hd2[((size_t)dc << 7) + pairoff];
    }
#pragma unroll
    for (int r = 0; r < 4; ++r) {
      int d = dd[r];
      bool nw = (d != cur);
      if (nw && cur >= 0) {  // divergent but load-free: 2 atomics only
        atomicAdd(&agg[cur * HH + c0], acc0);
        atomicAdd(&agg[cur * HH + c1], acc1);
      }
      acc0 = nw ? 0.f : acc0;
      acc1 = nw ? 0.f : acc1;
      hg0 = nw ? bl(xs[r].x) : hg0;
      hp0 = nw ? bh(xs[r].x) : hp0;
      hg1 = nw ? bl(xs[r].y) : hg1;
      hp1 = nw ? bh(xs[r].y) : hp1;
      cur = d;
      float zgN0 = zgv0[r] + bl(us[r].x) + hg0;
      float zsp0 = zsv0[r] + bh(us[r].x) + hp0;
      float zgN1 = zgv1[r] + bl(us[r].y) + hg1;
      float zsp1 = zsv1[r] + bh(us[r].y) + hp1;
      float sp0 = __builtin_amdgcn_logf(1.f + __builtin_amdgcn_exp2f(zsp0));
      float sp1 = __builtin_amdgcn_logf(1.f + __builtin_amdgcn_exp2f(zsp1));
      acc0 += sp0 * __builtin_amdgcn_rcpf(1.f + __builtin_amdgcn_exp2f(zgN0));
      acc1 += sp1 * __builtin_amdgcn_rcpf(1.f + __builtin_amdgcn_exp2f(zgN1));
    }
  }
  if (cur >= 0) {
    atomicAdd(&agg[cur * HH + c0], acc0);
    atomicAdd(&agg[cur * HH + c1], acc1);
  }
}

// -------- BN stats: per-column partial sum & sumsq, no atomics --------------
__global__ __launch_bounds__(256) void k_bn_stats(const float* __restrict__ agg,
                                                  float* __restrict__ part) {
  int col = threadIdx.x & 127, hlf = threadIdx.x >> 7;
  float s = 0.f, sq = 0.f;
  for (int row = blockIdx.x * 2 + hlf; row < NN; row += NPART * 2) {
    float v = agg[(size_t)row * HH + col];
    s += v; sq += v * v;
  }
  __shared__ float ls[256], lq[256];
  ls[threadIdx.x] = s; lq[threadIdx.x] = sq;
  __syncthreads();
  if (hlf == 0) {
    part[(size_t)blockIdx.x * 256 + col] = ls[col] + ls[col + 128];
    part[(size_t)blockIdx.x * 256 + 128 + col] = lq[col] + lq[col + 128];
  }
}

// bn_fin (256 thr): stats finalize; on last layer also zero g/gcnt for pool
__global__ __launch_bounds__(256) void k_bn_fin(const float* __restrict__ part,
                                                float* __restrict__ stats,
                                                const float* __restrict__ gam,
                                                const float* __restrict__ bet,
                                                float* __restrict__ g,
                                                float* __restrict__ gcnt,
                                                int zero_g) {
  int c = threadIdx.x;
  if (c < HH) {
    float s = 0.f, q = 0.f;
    for (int b = 0; b < NPART; b++) {
      s += part[(size_t)b * 256 + c];
      q += part[(size_t)b * 256 + 128 + c];
    }
    float mean = s / (float)NN;
    float var = q / (float)NN - mean * mean;
    float sc = rsqrtf(var + EPSF) * gam[c];
    stats[c] = sc;
    stats[HH + c] = bet[c] - mean * sc;
  }
  if (zero_g) {
    for (int i = threadIdx.x; i < BB * HH; i += 256) g[i] = 0.f;
    if (threadIdx.x < BB) gcnt[threadIdx.x] = 0.f;
  }
}

// -------- pooling with fused final BN-update: relu(h+agg*sc+sh) on the fly --
__global__ void k_pool(const float* __restrict__ h, const float* __restrict__ agg,
                       const float* __restrict__ stats, const int* __restrict__ batch,
                       float* __restrict__ g, float* __restrict__ gcnt) {
  int col = threadIdx.x;  // 128
  float sc = stats[col], sh = stats[128 + col];
  int chunk = (NN + gridDim.x - 1) / gridDim.x;
  int n0 = blockIdx.x * chunk, n1 = min(NN, n0 + chunk);
  if (n0 >= n1) return;
  int cur = batch[n0];
  float acc = 0.f, cnt = 0.f;
  for (int n = n0; n < n1; n++) {
    int bb = batch[n];
    if (bb != cur) {
      atomicAdd(&g[cur * HH + col], acc);
      if (col == 0) atomicAdd(&gcnt[cur], cnt);
      acc = 0.f; cnt = 0.f; cur = bb;
    }
    acc += fmaxf(h[(size_t)n * HH + col] + agg[(size_t)n * HH + col] * sc + sh, 0.f);
    cnt += 1.f;
  }
  atomicAdd(&g[cur * HH + col], acc);
  if (col == 0) atomicAdd(&gcnt[cur], cnt);
}

// ---- fc1 matmul over pooled rows + per-block BN column partials ------------
// 16 blocks x 256 thr; block handles 8 rows: y = (g/cnt) @ fc1w + fc1b
__global__ __launch_bounds__(256) void k_fc1(const float* __restrict__ g,
                                             const float* __restrict__ gcnt,
                                             const float* __restrict__ fc1w,
                                             const float* __restrict__ fc1b,
                                             float* __restrict__ y,
                                             float* __restrict__ part2) {
  __shared__ float w_s[HH * HH];   // 64 KB
  __shared__ float g_s[8 * HH];    // 4 KB
  __shared__ float ls[256], lq[256];
  int t = threadIdx.x;
  for (int i = t; i < HH * HH; i += 256) w_s[i] = fc1w[i];
  int r0 = blockIdx.x * 8;
  for (int i = t; i < 8 * HH; i += 256) {
    int r = i >> 7;
    g_s[i] = g[(size_t)(r0 + r) * HH + (i & 127)] / fmaxf(gcnt[r0 + r], 1.f);
  }
  __syncthreads();
  int c = t & 127, rh = t >> 7;  // rh in 0..1, 4 rows each
  float s = 0.f, sq = 0.f;
  for (int rr = 0; rr < 4; rr++) {
    int r = rh * 4 + rr;
    float acc = fc1b[c];
    for (int k = 0; k < HH; k++) acc += g_s[r * HH + k] * w_s[k * HH + c];
    y[(size_t)(r0 + r) * HH + c] = acc;
    s += acc; sq += acc * acc;
  }
  ls[t] = s; lq[t] = sq;
  __syncthreads();
  if (rh == 0) {
    part2[blockIdx.x * 256 + c] = ls[c] + ls[c + 128];
    part2[blockIdx.x * 256 + 128 + c] = lq[c] + lq[c + 128];
  }
}

// ---- final2: BN finalize over 16 partials, relu, out = y' @ ow + ob --------
__global__ __launch_bounds__(256) void k_final2(const float* __restrict__ part2,
                                                const float* __restrict__ y,
                                                const float* __restrict__ gam,
                                                const float* __restrict__ bet,
                                                const float* __restrict__ ow,
                                                const float* __restrict__ ob,
                                                float* __restrict__ out) {
  __shared__ float sc_s[HH], sh_s[HH];
  __shared__ float ls[256];
  int t = threadIdx.x;
  if (t < HH) {
    float s = 0.f, q = 0.f;
    for (int b = 0; b < 16; b++) {
      s += part2[b * 256 + t];
      q += part2[b * 256 + 128 + t];
    }
    float mean = s / (float)BB;
    float var = q / (float)BB - mean * mean;
    float scv = rsqrtf(var + EPSF) * gam[t];
    sc_s[t] = scv;
    sh_s[t] = bet[t] - mean * scv;
  }
  __syncthreads();
  int r = t >> 1, hf = t & 1;
  float acc = 0.f;
  for (int k = hf * 64; k < hf * 64 + 64; k++) {
    float v = fmaxf(y[(size_t)r * HH + k] * sc_s[k] + sh_s[k], 0.f);
    acc += v * ow[k];
  }
  ls[t] = acc;
  __syncthreads();
  if (hf == 0) out[r] = ls[t] + ls[t + 1] + ob[0];
}

extern "C" void kernel_launch(void* const* d_in, const int* in_sizes, int n_in,
                              void* d_out, int out_size, void* d_ws, size_t ws_size,
                              hipStream_t stream) {
  (void)in_sizes; (void)n_in; (void)out_size; (void)ws_size;
  const float* node_feats = (const float*)d_in[0];
  const int* edge_index = (const int*)d_in[1];
  const float* edge_feats = (const float*)d_in[2];
  const int* batch = (const int*)d_in[3];
  const float* embed_w = (const float*)d_in[4];
  const float* embed_b = (const float*)d_in[5];
  const float* conv_wsrc = (const float*)d_in[6];
  const float* conv_wdst = (const float*)d_in[7];
  const float* conv_we = (const float*)d_in[8];
  const float* conv_b = (const float*)d_in[9];
  const float* bn_gamma = (const float*)d_in[10];
  const float* bn_beta = (const float*)d_in[11];
  const float* fc1_w = (const float*)d_in[12];
  const float* fc1_b = (const float*)d_in[13];
  const float* fc_bn_gamma = (const float*)d_in[14];
  const float* fc_bn_beta = (const float*)d_in[15];
  const float* out_w = (const float*)d_in[16];
  const float* out_b = (const float*)d_in[17];

  char* ws = (char*)d_ws;
  size_t o = 0;
  float* h = (float*)(ws + o);              o += (size_t)NN * HH * 4;      // 51.2 MB
  unsigned int* hs2 = (unsigned int*)(ws + o); o += (size_t)NN * 128 * 4;  // 51.2 MB
  unsigned int* hd2 = (unsigned int*)(ws + o); o += (size_t)NN * 128 * 4;  // 51.2 MB
  float* agg = (float*)(ws + o);            o += (size_t)NN * HH * 4;      // 51.2 MB
  short* efp = (short*)(ws + o);            o += (size_t)ECAP * 32 * 2;    // 104.9 MB
  int* src_s = (int*)(ws + o);              o += (size_t)ECAP * 4;         // 6.6 MB
  int* dst_s = (int*)(ws + o);              o += (size_t)ECAP * 4;         // 6.6 MB
  int* cnt = (int*)(ws + o);                o += (size_t)NN * 4;
  int* off = (int*)(ws + o);                o += (size_t)NN * 4;
  short* wt3 = (short*)(ws + o);            o += (size_t)3 * 2 * 256 * 128 * 2;
  short* Web3 = (short*)(ws + o);           o += (size_t)3 * 256 * 32 * 2;
  float* part = (float*)(ws + o);           o += (size_t)NPART * 256 * 4;  // 512 KB
  float* part2 = (float*)(ws + o);          o += (size_t)16 * 256 * 4;
  float* stats = (float*)(ws + o);          o += 256 * 4;
  float* g = (float*)(ws + o);              o += (size_t)BB * HH * 4;
  float* y = (float*)(ws + o);              o += (size_t)BB * HH * 4;
  float* gcnt = (float*)(ws + o);           o += BB * 4;

  const int* src = edge_index;
  const int* dst = edge_index + EE;

  // one-time: all-layer weight prep (+cnt zeroing), counting sort, ef pre-cast
  k_wprep3<<<(3 * 73728 + 255) / 256, 256, 0, stream>>>(conv_wsrc, conv_wdst,
                                                        conv_we, conv_b, wt3, Web3, cnt);
  k_hist<<<2048, 256, 0, stream>>>(dst, cnt);
  k_scan<<<1, 1024, 0, stream>>>(cnt, off);
  k_scatter<<<2048, 256, 0, stream>>>(src, dst, edge_feats, off, src_s, dst_s, efp);

  k_embed<<<512, 256, 0, stream>>>(node_feats, embed_w, embed_b, h);

  for (int i = 0; i < 3; i++) {
    // fused: applies previous layer's BN-update to h (i>0), zeroes agg,
    // produces hs2/hd2
    k_node_mm<<<(NN + 63) / 64, 256, 0, stream>>>(h, agg, stats,
                                                  wt3 + (size_t)i * 65536,
                                                  hs2, hd2, i > 0 ? 1 : 0);
    k_edge_v8<<<NBLK, 256, 0, stream>>>(hs2, hd2, efp, src_s, dst_s,
                                        Web3 + (size_t)i * 8192, agg);
    k_bn_stats<<<NPART, 256, 0, stream>>>(agg, part);
    k_bn_fin<<<1, 256, 0, stream>>>(part, stats, bn_gamma + i * HH,
                                    bn_beta + i * HH, g, gcnt, i == 2 ? 1 : 0);
  }

  // pool with fused final-layer BN-update, then split head
  k_pool<<<1024, 128, 0, stream>>>(h, agg, stats, batch, g, gcnt);
  k_fc1<<<16, 256, 0, stream>>>(g, gcnt, fc1_w, fc1_b, y, part2);
  k_final2<<<1, 256, 0, stream>>>(part2, y, fc_bn_gamma, fc_bn_beta,
                                  out_w, out_b, (float*)d_out);
}

// Round 14
// 1760.370 us; speedup vs baseline: 1.1451x; 1.1451x over previous
//
#include <hip/hip_runtime.h>
#include <hip/hip_bf16.h>

#define NN 100000
#define EE 1600000
#define HH 128
#define NDIM 91
#define EDIM 20
#define BB 128
#define EPSF 1e-5f
#define NBLK 4096
#define PER 400                 // edges per block (4 kg-subranges of 100)
#define ECAP (NBLK * PER)       // 1,638,400 (padded)
#define LN2I 1.44269504f
#define NPART 512               // bn_stats partial blocks

typedef __attribute__((ext_vector_type(8))) short short8v;
typedef __attribute__((ext_vector_type(4))) float f32x4;

__device__ __forceinline__ short f2bs(float x) {
  __hip_bfloat16 b = __float2bfloat16(x);
  return *reinterpret_cast<short*>(&b);
}
__device__ __forceinline__ float bl(unsigned int u) {  // lo bf16 -> f32
  union { unsigned int i; float f; } x; x.i = u << 16; return x.f;
}
__device__ __forceinline__ float bh(unsigned int u) {  // hi bf16 -> f32
  union { unsigned int i; float f; } x; x.i = u & 0xffff0000u; return x.f;
}

// ---------------- embed: h = nf @ W + b  (N x 91 @ 91 x 128) ----------------
__global__ __launch_bounds__(256) void k_embed(const float* __restrict__ nf,
                                               const float* __restrict__ W,
                                               const float* __restrict__ b,
                                               float* __restrict__ h) {
  __shared__ float w_s[NDIM * HH];
  __shared__ float b_s[HH];
  __shared__ float a_s[16 * 92];
  for (int i = threadIdx.x; i < NDIM * HH; i += 256) w_s[i] = W[i];
  if (threadIdx.x < HH) b_s[threadIdx.x] = b[threadIdx.x];
  __syncthreads();
  int col = threadIdx.x & 127, rs = threadIdx.x >> 7;
  for (int base = blockIdx.x * 16; base < NN; base += gridDim.x * 16) {
    int nrows = min(16, NN - base);
    int tot = nrows * NDIM;
    for (int i = threadIdx.x; i < tot; i += 256) {
      int r = i / NDIM;
      a_s[r * 92 + (i - r * NDIM)] = nf[(size_t)base * NDIM + i];
    }
    __syncthreads();
    float acc[8];
#pragma unroll
    for (int r = 0; r < 8; r++) acc[r] = 0.f;
    for (int k = 0; k < NDIM; k++) {
      float w = w_s[k * HH + col];
#pragma unroll
      for (int r = 0; r < 8; r++) acc[r] += a_s[(rs * 8 + r) * 92 + k] * w;
    }
#pragma unroll
    for (int r = 0; r < 8; r++) {
      int row = base + rs * 8 + r;
      if (row < NN) h[(size_t)row * HH + col] = acc[r] + b_s[col];
    }
    __syncthreads();
  }
}

// --- one-shot weight prep for ALL 3 layers + cnt zeroing --------------------
__global__ __launch_bounds__(256) void k_wprep3(const float* __restrict__ conv_wsrc,
                                                const float* __restrict__ conv_wdst,
                                                const float* __restrict__ conv_we,
                                                const float* __restrict__ conv_b,
                                                short* __restrict__ wt3,
                                                short* __restrict__ Web3,
                                                int* __restrict__ cnt) {
  int i = blockIdx.x * 256 + threadIdx.x;
  if (i < NN) cnt[i] = 0;
  if (i >= 3 * 73728) return;
  int layer = i / 73728;
  int j = i - layer * 73728;
  if (j < 65536) {
    int mat = j >> 15;
    int r = (j >> 7) & 255;
    int k = j & 127;
    const float* W = (mat ? conv_wdst : conv_wsrc) + (size_t)layer * HH * 256;
    wt3[(size_t)layer * 65536 + j] = f2bs(W[k * 256 + r]);
  } else {
    int jj = j - 65536;
    int c = jj >> 5, k = jj & 31;
    const float* We = conv_we + (size_t)layer * EDIM * 256;
    const float* bias = conv_b + (size_t)layer * 256;
    float v = (k < EDIM) ? We[k * 256 + c] : (k == EDIM ? bias[c] : 0.f);
    float sc = (c < 128) ? -LN2I : LN2I;
    Web3[(size_t)layer * 8192 + jj] = f2bs(v * sc);
  }
}

// ------------- node_mm (merged mats + fused BN-update + agg zeroing) -------
__global__ __launch_bounds__(256) void k_node_mm(float* __restrict__ h,
                                                 float* __restrict__ agg,
                                                 const float* __restrict__ stats,
                                                 const short* __restrict__ wt,
                                                 unsigned int* __restrict__ hs2,
                                                 unsigned int* __restrict__ hd2,
                                                 int apply) {
  __shared__ short hlds[64 * 128];  // 16 KB bf16 A-tile
  __shared__ float st_s[256];
  int base = blockIdx.x * 64;
  int t = threadIdx.x;
  if (apply) {
    if (t < 256) st_s[t] = stats[t];
    __syncthreads();
  }
  const float4 z4 = make_float4(0.f, 0.f, 0.f, 0.f);
#pragma unroll
  for (int p = 0; p < 4; p++) {
    int e0 = (p * 256 + t) * 8;
    int row = e0 >> 7, col = e0 & 127;
    int gr = base + row;
    float4 f0 = z4, f1 = z4;
    if (gr < NN) {
      f0 = *(const float4*)&h[(size_t)gr * 128 + col];
      f1 = *(const float4*)&h[(size_t)gr * 128 + col + 4];
      if (apply) {
        float4 a0 = *(const float4*)&agg[(size_t)gr * 128 + col];
        float4 a1 = *(const float4*)&agg[(size_t)gr * 128 + col + 4];
        f0.x = fmaxf(f0.x + a0.x * st_s[col] + st_s[128 + col], 0.f);
        f0.y = fmaxf(f0.y + a0.y * st_s[col + 1] + st_s[129 + col], 0.f);
        f0.z = fmaxf(f0.z + a0.z * st_s[col + 2] + st_s[130 + col], 0.f);
        f0.w = fmaxf(f0.w + a0.w * st_s[col + 3] + st_s[131 + col], 0.f);
        f1.x = fmaxf(f1.x + a1.x * st_s[col + 4] + st_s[132 + col], 0.f);
        f1.y = fmaxf(f1.y + a1.y * st_s[col + 5] + st_s[133 + col], 0.f);
        f1.z = fmaxf(f1.z + a1.z * st_s[col + 6] + st_s[134 + col], 0.f);
        f1.w = fmaxf(f1.w + a1.w * st_s[col + 7] + st_s[135 + col], 0.f);
        *(float4*)&h[(size_t)gr * 128 + col] = f0;
        *(float4*)&h[(size_t)gr * 128 + col + 4] = f1;
      }
      // zero agg for the next layer's edge accumulation (replaces memset)
      *(float4*)&agg[(size_t)gr * 128 + col] = z4;
      *(float4*)&agg[(size_t)gr * 128 + col + 4] = z4;
    }
    short8v u;
    u[0] = f2bs(f0.x); u[1] = f2bs(f0.y); u[2] = f2bs(f0.z); u[3] = f2bs(f0.w);
    u[4] = f2bs(f1.x); u[5] = f2bs(f1.y); u[6] = f2bs(f1.z); u[7] = f2bs(f1.w);
    *(short8v*)&hlds[e0] = u;
  }
  __syncthreads();
  int w = t >> 6, l = t & 63;
  int cl = l & 15, kg = l >> 4;
  bool full = (base + 64 <= NN);
  short8v a[4];
#pragma unroll
  for (int kk = 0; kk < 4; kk++)
    a[kk] = *(const short8v*)&hlds[(w * 16 + cl) * 128 + kk * 32 + kg * 8];
#pragma unroll
  for (int mat = 0; mat < 2; mat++) {
    const short* wtm = wt + mat * 256 * 128;
    unsigned int* out = mat ? hd2 : hs2;
    f32x4 acc[16];
#pragma unroll
    for (int ct = 0; ct < 16; ct++) acc[ct] = (f32x4)(0.f);
#pragma unroll
    for (int ct = 0; ct < 16; ct++) {
#pragma unroll
      for (int kk = 0; kk < 4; kk++) {
        short8v b = *(const short8v*)&wtm[(ct * 16 + cl) * 128 + kk * 32 + kg * 8];
        acc[ct] = __builtin_amdgcn_mfma_f32_16x16x32_bf16(a[kk], b, acc[ct], 0, 0, 0);
      }
    }
    // paired-column epilogue: ct=2j,2j+1 -> adjacent slots -> uint2 store
#pragma unroll
    for (int j = 0; j < 4; j++) {
#pragma unroll
      for (int r = 0; r < 4; r++) {
        int gr = base + w * 16 + kg * 4 + r;
        if (full || gr < NN) {
          unsigned short g0 = (unsigned short)f2bs(-LN2I * acc[2 * j][r]);
          unsigned short s0 = (unsigned short)f2bs(LN2I * acc[2 * j + 8][r]);
          unsigned short g1 = (unsigned short)f2bs(-LN2I * acc[2 * j + 1][r]);
          unsigned short s1 = (unsigned short)f2bs(LN2I * acc[2 * j + 9][r]);
          uint2 val;
          val.x = (unsigned int)g0 | ((unsigned int)s0 << 16);
          val.y = (unsigned int)g1 | ((unsigned int)s1 << 16);
          *(uint2*)&out[(size_t)gr * 128 + j * 32 + (cl << 1)] = val;
        }
      }
    }
  }
}

// ---------------- counting sort by dst: hist, scan, scatter -----------------
__global__ __launch_bounds__(256) void k_hist(const int* __restrict__ dst,
                                              int* __restrict__ cnt) {
  for (int e = blockIdx.x * 256 + threadIdx.x; e < EE; e += gridDim.x * 256)
    atomicAdd(&cnt[dst[e]], 1);
}

__global__ __launch_bounds__(1024) void k_scan(const int* __restrict__ cnt,
                                               int* __restrict__ off) {
  __shared__ int ps[1024];
  int t = threadIdx.x;
  const int R = (NN + 1023) / 1024;
  int b0 = t * R, b1 = min(NN, b0 + R);
  int s = 0;
  for (int i = b0; i < b1; i++) s += cnt[i];
  ps[t] = s;
  __syncthreads();
  for (int d = 1; d < 1024; d <<= 1) {
    int v = (t >= d) ? ps[t - d] : 0;
    __syncthreads();
    ps[t] += v;
    __syncthreads();
  }
  int run = (t == 0) ? 0 : ps[t - 1];
  for (int i = b0; i < b1; i++) {
    off[i] = run;
    run += cnt[i];
  }
}

// scatter (+tail pad): sorted idx + ef rows bf16 [32] (k20=1.0 bias hook)
__global__ __launch_bounds__(256) void k_scatter(const int* __restrict__ src,
                                                 const int* __restrict__ dst,
                                                 const float* __restrict__ ef,
                                                 int* __restrict__ off,
                                                 int* __restrict__ src_s,
                                                 int* __restrict__ dst_s,
                                                 short* __restrict__ efp) {
  for (int e = blockIdx.x * 256 + threadIdx.x; e < ECAP; e += gridDim.x * 256) {
    if (e < EE) {
      int d = dst[e];
      int pos = atomicAdd(&off[d], 1);
      src_s[pos] = src[e];
      dst_s[pos] = d;
      const float4* in = (const float4*)&ef[(size_t)e * EDIM];
      float4 q0 = in[0], q1 = in[1], q2 = in[2], q3 = in[3], q4 = in[4];
      short8v u0, u1, u2, u3;
      u0[0] = f2bs(q0.x); u0[1] = f2bs(q0.y); u0[2] = f2bs(q0.z); u0[3] = f2bs(q0.w);
      u0[4] = f2bs(q1.x); u0[5] = f2bs(q1.y); u0[6] = f2bs(q1.z); u0[7] = f2bs(q1.w);
      u1[0] = f2bs(q2.x); u1[1] = f2bs(q2.y); u1[2] = f2bs(q2.z); u1[3] = f2bs(q2.w);
      u1[4] = f2bs(q3.x); u1[5] = f2bs(q3.y); u1[6] = f2bs(q3.z); u1[7] = f2bs(q3.w);
      u2[0] = f2bs(q4.x); u2[1] = f2bs(q4.y); u2[2] = f2bs(q4.z); u2[3] = f2bs(q4.w);
      u2[4] = f2bs(1.0f); u2[5] = 0; u2[6] = 0; u2[7] = 0;
      u3 = (short8v)(short)0;
      short8v* op = (short8v*)&efp[(size_t)pos * 32];
      op[0] = u0; op[1] = u1; op[2] = u2; op[3] = u3;
    } else {
      src_s[e] = 0;
      dst_s[e] = -2;
      short8v z = (short8v)(short)0;
      short8v* op = (short8v*)&efp[(size_t)e * 32];
      op[0] = z; op[1] = z; op[2] = z; op[3] = z;
    }
  }
}

// ---- edge kernel v8 (round-12 config restored: plain launch_bounds(256),
// ---- VGPR 44, ~50% occupancy = measured local optimum).
// ---- Barrier-free, zero LDS, run-cached hd, all loads hoisted out of the
// ---- divergent region. (256,8) hint REGRESSED (r13: VGPR squeezed to 32,
// ---- remat + cache thrash, FETCH +28%); do not re-add.
__global__ __launch_bounds__(256) void k_edge_v8(
    const unsigned int* __restrict__ hs2, const unsigned int* __restrict__ hd2,
    const short* __restrict__ efp, const int* __restrict__ srcp,
    const int* __restrict__ dstp, const short* __restrict__ Web,
    float* __restrict__ agg) {
  const int i0 = blockIdx.x * PER;
  int t = threadIdx.x;
  int w = t >> 6, l = t & 63, cl = l & 15, kg = l >> 4;
  int c0 = w * 32 + cl, c1 = c0 + 16;
  int pairoff = w * 32 + (cl << 1);
  short8v bg0 = *(const short8v*)&Web[c0 * 32 + kg * 8];
  short8v bg1 = *(const short8v*)&Web[c1 * 32 + kg * 8];
  short8v bs0 = *(const short8v*)&Web[(128 + c0) * 32 + kg * 8];
  short8v bs1 = *(const short8v*)&Web[(128 + c1) * 32 + kg * 8];
  int cur = -1;
  float acc0 = 0.f, acc1 = 0.f;
  float hg0 = 0.f, hp0 = 0.f, hg1 = 0.f, hp1 = 0.f;
  const int o_a_base = i0 + (cl >> 2) * 100 + (cl & 3);
  const int o_e_base = i0 + kg * 100;
  for (int it = 0; it < 25; ++it) {
    int off4 = it * 4;
    short8v a = *(const short8v*)&efp[(size_t)(o_a_base + off4) * 32 + kg * 8];
    f32x4 zgv0 = __builtin_amdgcn_mfma_f32_16x16x32_bf16(a, bg0, (f32x4)(0.f), 0, 0, 0);
    f32x4 zgv1 = __builtin_amdgcn_mfma_f32_16x16x32_bf16(a, bg1, (f32x4)(0.f), 0, 0, 0);
    f32x4 zsv0 = __builtin_amdgcn_mfma_f32_16x16x32_bf16(a, bs0, (f32x4)(0.f), 0, 0, 0);
    f32x4 zsv1 = __builtin_amdgcn_mfma_f32_16x16x32_bf16(a, bs1, (f32x4)(0.f), 0, 0, 0);
    int o_e = o_e_base + off4;
    int4 s4 = *(const int4*)&srcp[o_e];
    int4 d4 = *(const int4*)&dstp[o_e];
    int ss[4] = {s4.x, s4.y, s4.z, s4.w};
    int dd[4] = {d4.x, d4.y, d4.z, d4.w};
    // hoisted gathers: hs2 per edge + unconditional hd2 (clamped, L1-repeated)
    uint2 us[4], xs[4];
#pragma unroll
    for (int r = 0; r < 4; ++r) {
      us[r] = *(const uint2*)&hs2[((size_t)ss[r] << 7) + pairoff];
      int dc = dd[r] < 0 ? 0 : dd[r];
      xs[r] = *(const uint2*)&hd2[((size_t)dc << 7) + pairoff];
    }
#pragma unroll
    for (int r = 0; r < 4; ++r) {
      int d = dd[r];
      bool nw = (d != cur);
      if (nw && cur >= 0) {  // divergent but load-free: 2 atomics only
        atomicAdd(&agg[cur * HH + c0], acc0);
        atomicAdd(&agg[cur * HH + c1], acc1);
      }
      acc0 = nw ? 0.f : acc0;
      acc1 = nw ? 0.f : acc1;
      hg0 = nw ? bl(xs[r].x) : hg0;
      hp0 = nw ? bh(xs[r].x) : hp0;
      hg1 = nw ? bl(xs[r].y) : hg1;
      hp1 = nw ? bh(xs[r].y) : hp1;
      cur = d;
      float zgN0 = zgv0[r] + bl(us[r].x) + hg0;
      float zsp0 = zsv0[r] + bh(us[r].x) + hp0;
      float zgN1 = zgv1[r] + bl(us[r].y) + hg1;
      float zsp1 = zsv1[r] + bh(us[r].y) + hp1;
      float sp0 = __builtin_amdgcn_logf(1.f + __builtin_amdgcn_exp2f(zsp0));
      float sp1 = __builtin_amdgcn_logf(1.f + __builtin_amdgcn_exp2f(zsp1));
      acc0 += sp0 * __builtin_amdgcn_rcpf(1.f + __builtin_amdgcn_exp2f(zgN0));
      acc1 += sp1 * __builtin_amdgcn_rcpf(1.f + __builtin_amdgcn_exp2f(zgN1));
    }
  }
  if (cur >= 0) {
    atomicAdd(&agg[cur * HH + c0], acc0);
    atomicAdd(&agg[cur * HH + c1], acc1);
  }
}

// -------- BN stats: per-column partial sum & sumsq, no atomics --------------
__global__ __launch_bounds__(256) void k_bn_stats(const float* __restrict__ agg,
                                                  float* __restrict__ part) {
  int col = threadIdx.x & 127, hlf = threadIdx.x >> 7;
  float s = 0.f, sq = 0.f;
  for (int row = blockIdx.x * 2 + hlf; row < NN; row += NPART * 2) {
    float v = agg[(size_t)row * HH + col];
    s += v; sq += v * v;
  }
  __shared__ float ls[256], lq[256];
  ls[threadIdx.x] = s; lq[threadIdx.x] = sq;
  __syncthreads();
  if (hlf == 0) {
    part[(size_t)blockIdx.x * 256 + col] = ls[col] + ls[col + 128];
    part[(size_t)blockIdx.x * 256 + 128 + col] = lq[col] + lq[col + 128];
  }
}

// bn_fin (256 thr): stats finalize; on last layer also zero g/gcnt for pool
__global__ __launch_bounds__(256) void k_bn_fin(const float* __restrict__ part,
                                                float* __restrict__ stats,
                                                const float* __restrict__ gam,
                                                const float* __restrict__ bet,
                                                float* __restrict__ g,
                                                float* __restrict__ gcnt,
                                                int zero_g) {
  int c = threadIdx.x;
  if (c < HH) {
    float s = 0.f, q = 0.f;
    for (int b = 0; b < NPART; b++) {
      s += part[(size_t)b * 256 + c];
      q += part[(size_t)b * 256 + 128 + c];
    }
    float mean = s / (float)NN;
    float var = q / (float)NN - mean * mean;
    float sc = rsqrtf(var + EPSF) * gam[c];
    stats[c] = sc;
    stats[HH + c] = bet[c] - mean * sc;
  }
  if (zero_g) {
    for (int i = threadIdx.x; i < BB * HH; i += 256) g[i] = 0.f;
    if (threadIdx.x < BB) gcnt[threadIdx.x] = 0.f;
  }
}

// -------- pooling with fused final BN-update: relu(h+agg*sc+sh) on the fly --
__global__ void k_pool(const float* __restrict__ h, const float* __restrict__ agg,
                       const float* __restrict__ stats, const int* __restrict__ batch,
                       float* __restrict__ g, float* __restrict__ gcnt) {
  int col = threadIdx.x;  // 128
  float sc = stats[col], sh = stats[128 + col];
  int chunk = (NN + gridDim.x - 1) / gridDim.x;
  int n0 = blockIdx.x * chunk, n1 = min(NN, n0 + chunk);
  if (n0 >= n1) return;
  int cur = batch[n0];
  float acc = 0.f, cnt = 0.f;
  for (int n = n0; n < n1; n++) {
    int bb = batch[n];
    if (bb != cur) {
      atomicAdd(&g[cur * HH + col], acc);
      if (col == 0) atomicAdd(&gcnt[cur], cnt);
      acc = 0.f; cnt = 0.f; cur = bb;
    }
    acc += fmaxf(h[(size_t)n * HH + col] + agg[(size_t)n * HH + col] * sc + sh, 0.f);
    cnt += 1.f;
  }
  atomicAdd(&g[cur * HH + col], acc);
  if (col == 0) atomicAdd(&gcnt[cur], cnt);
}

// ---- fc1 matmul over pooled rows + per-block BN column partials ------------
// 16 blocks x 256 thr; block handles 8 rows: y = (g/cnt) @ fc1w + fc1b
__global__ __launch_bounds__(256) void k_fc1(const float* __restrict__ g,
                                             const float* __restrict__ gcnt,
                                             const float* __restrict__ fc1w,
                                             const float* __restrict__ fc1b,
                                             float* __restrict__ y,
                                             float* __restrict__ part2) {
  __shared__ float w_s[HH * HH];   // 64 KB
  __shared__ float g_s[8 * HH];    // 4 KB
  __shared__ float ls[256], lq[256];
  int t = threadIdx.x;
  for (int i = t; i < HH * HH; i += 256) w_s[i] = fc1w[i];
  int r0 = blockIdx.x * 8;
  for (int i = t; i < 8 * HH; i += 256) {
    int r = i >> 7;
    g_s[i] = g[(size_t)(r0 + r) * HH + (i & 127)] / fmaxf(gcnt[r0 + r], 1.f);
  }
  __syncthreads();
  int c = t & 127, rh = t >> 7;  // rh in 0..1, 4 rows each
  float s = 0.f, sq = 0.f;
  for (int rr = 0; rr < 4; rr++) {
    int r = rh * 4 + rr;
    float acc = fc1b[c];
    for (int k = 0; k < HH; k++) acc += g_s[r * HH + k] * w_s[k * HH + c];
    y[(size_t)(r0 + r) * HH + c] = acc;
    s += acc; sq += acc * acc;
  }
  ls[t] = s; lq[t] = sq;
  __syncthreads();
  if (rh == 0) {
    part2[blockIdx.x * 256 + c] = ls[c] + ls[c + 128];
    part2[blockIdx.x * 256 + 128 + c] = lq[c] + lq[c + 128];
  }
}

// ---- final2: BN finalize over 16 partials, relu, out = y' @ ow + ob --------
__global__ __launch_bounds__(256) void k_final2(const float* __restrict__ part2,
                                                const float* __restrict__ y,
                                                const float* __restrict__ gam,
                                                const float* __restrict__ bet,
                                                const float* __restrict__ ow,
                                                const float* __restrict__ ob,
                                                float* __restrict__ out) {
  __shared__ float sc_s[HH], sh_s[HH];
  __shared__ float ls[256];
  int t = threadIdx.x;
  if (t < HH) {
    float s = 0.f, q = 0.f;
    for (int b = 0; b < 16; b++) {
      s += part2[b * 256 + t];
      q += part2[b * 256 + 128 + t];
    }
    float mean = s / (float)BB;
    float var = q / (float)BB - mean * mean;
    float scv = rsqrtf(var + EPSF) * gam[t];
    sc_s[t] = scv;
    sh_s[t] = bet[t] - mean * scv;
  }
  __syncthreads();
  int r = t >> 1, hf = t & 1;
  float acc = 0.f;
  for (int k = hf * 64; k < hf * 64 + 64; k++) {
    float v = fmaxf(y[(size_t)r * HH + k] * sc_s[k] + sh_s[k], 0.f);
    acc += v * ow[k];
  }
  ls[t] = acc;
  __syncthreads();
  if (hf == 0) out[r] = ls[t] + ls[t + 1] + ob[0];
}

extern "C" void kernel_launch(void* const* d_in, const int* in_sizes, int n_in,
                              void* d_out, int out_size, void* d_ws, size_t ws_size,
                              hipStream_t stream) {
  (void)in_sizes; (void)n_in; (void)out_size; (void)ws_size;
  const float* node_feats = (const float*)d_in[0];
  const int* edge_index = (const int*)d_in[1];
  const float* edge_feats = (const float*)d_in[2];
  const int* batch = (const int*)d_in[3];
  const float* embed_w = (const float*)d_in[4];
  const float* embed_b = (const float*)d_in[5];
  const float* conv_wsrc = (const float*)d_in[6];
  const float* conv_wdst = (const float*)d_in[7];
  const float* conv_we = (const float*)d_in[8];
  const float* conv_b = (const float*)d_in[9];
  const float* bn_gamma = (const float*)d_in[10];
  const float* bn_beta = (const float*)d_in[11];
  const float* fc1_w = (const float*)d_in[12];
  const float* fc1_b = (const float*)d_in[13];
  const float* fc_bn_gamma = (const float*)d_in[14];
  const float* fc_bn_beta = (const float*)d_in[15];
  const float* out_w = (const float*)d_in[16];
  const float* out_b = (const float*)d_in[17];

  char* ws = (char*)d_ws;
  size_t o = 0;
  float* h = (float*)(ws + o);              o += (size_t)NN * HH * 4;      // 51.2 MB
  unsigned int* hs2 = (unsigned int*)(ws + o); o += (size_t)NN * 128 * 4;  // 51.2 MB
  unsigned int* hd2 = (unsigned int*)(ws + o); o += (size_t)NN * 128 * 4;  // 51.2 MB
  float* agg = (float*)(ws + o);            o += (size_t)NN * HH * 4;      // 51.2 MB
  short* efp = (short*)(ws + o);            o += (size_t)ECAP * 32 * 2;    // 104.9 MB
  int* src_s = (int*)(ws + o);              o += (size_t)ECAP * 4;         // 6.6 MB
  int* dst_s = (int*)(ws + o);              o += (size_t)ECAP * 4;         // 6.6 MB
  int* cnt = (int*)(ws + o);                o += (size_t)NN * 4;
  int* off = (int*)(ws + o);                o += (size_t)NN * 4;
  short* wt3 = (short*)(ws + o);            o += (size_t)3 * 2 * 256 * 128 * 2;
  short* Web3 = (short*)(ws + o);           o += (size_t)3 * 256 * 32 * 2;
  float* part = (float*)(ws + o);           o += (size_t)NPART * 256 * 4;  // 512 KB
  float* part2 = (float*)(ws + o);          o += (size_t)16 * 256 * 4;
  float* stats = (float*)(ws + o);          o += 256 * 4;
  float* g = (float*)(ws + o);              o += (size_t)BB * HH * 4;
  float* y = (float*)(ws + o);              o += (size_t)BB * HH * 4;
  float* gcnt = (float*)(ws + o);           o += BB * 4;

  const int* src = edge_index;
  const int* dst = edge_index + EE;

  // one-time: all-layer weight prep (+cnt zeroing), counting sort, ef pre-cast
  k_wprep3<<<(3 * 73728 + 255) / 256, 256, 0, stream>>>(conv_wsrc, conv_wdst,
                                                        conv_we, conv_b, wt3, Web3, cnt);
  k_hist<<<2048, 256, 0, stream>>>(dst, cnt);
  k_scan<<<1, 1024, 0, stream>>>(cnt, off);
  k_scatter<<<2048, 256, 0, stream>>>(src, dst, edge_feats, off, src_s, dst_s, efp);

  k_embed<<<512, 256, 0, stream>>>(node_feats, embed_w, embed_b, h);

  for (int i = 0; i < 3; i++) {
    // fused: applies previous layer's BN-update to h (i>0), zeroes agg,
    // produces hs2/hd2
    k_node_mm<<<(NN + 63) / 64, 256, 0, stream>>>(h, agg, stats,
                                                  wt3 + (size_t)i * 65536,
                                                  hs2, hd2, i > 0 ? 1 : 0);
    k_edge_v8<<<NBLK, 256, 0, stream>>>(hs2, hd2, efp, src_s, dst_s,
                                        Web3 + (size_t)i * 8192, agg);
    k_bn_stats<<<NPART, 256, 0, stream>>>(agg, part);
    k_bn_fin<<<1, 256, 0, stream>>>(part, stats, bn_gamma + i * HH,
                                    bn_beta + i * HH, g, gcnt, i == 2 ? 1 : 0);
  }

  // pool with fused final-layer BN-update, then split head
  k_pool<<<1024, 128, 0, stream>>>(h, agg, stats, batch, g, gcnt);
  k_fc1<<<16, 256, 0, stream>>>(g, gcnt, fc1_w, fc1_b, y, part2);
  k_final2<<<1, 256, 0, stream>>>(part2, y, fc_bn_gamma, fc_bn_beta,
                                  out_w, out_b, (float*)d_out);
}